// Round 3
// baseline (97.127 us; speedup 1.0000x reference)
//
#include <hip/hip_runtime.h>

// SpaceToDepth bs=2: x0 (16,64,256,256) f32 -> y (16,256,128,128) f32, plus x1 (16,) passthrough.
// y[b, hin*128 + win*64 + c, ho, wo] = x0[b, c, 2*ho + hin, 2*wo + win]
// d_out = [ y flat (67,108,864 floats) | x1 (16 floats) ]
//
// R3: OUTPUT-centric mapping. Each wave writes 1KB-contiguous runs (lanes cover
// wo4 0..31 x two consecutive ho of the SAME channel d); each block extends that
// to 4KB per channel plane. Reads split into 2x512B segments per instruction
// (the reverse trade vs R2). Same 512 MiB total traffic.

typedef float v4f __attribute__((ext_vector_type(4)));

constexpr long long Y_ELEMS  = 67108864;   // 16*256*128*128
constexpr long long S1_OFF4  = 262144;     // 64*128*32 float4s (channel d -> d+64)

__global__ void __launch_bounds__(256) s2d_kernel(const v4f* __restrict__ in,
                                                  const float* __restrict__ x1,
                                                  v4f* __restrict__ out) {
    long long t = (long long)blockIdx.x * blockDim.x + threadIdx.x;

    // t -> (b, hin, c, ho, wo4): wo4 fastest so waves cover contiguous output
    int wo4 = (int)(t & 31);
    int ho  = (int)((t >> 5) & 127);
    int c   = (int)((t >> 12) & 63);
    int hin = (int)((t >> 18) & 1);
    int b   = (int)(t >> 19);

    // input: row (b, c, h=2*ho+hin), 8 floats starting at 8*wo4 (32B, aligned)
    long long irow = (((long long)b * 64 + c) * 256 + (2 * ho + hin));
    long long i4   = irow * 64 + (wo4 << 1);          // input float4 index
    v4f v0 = in[i4];
    v4f v1 = in[i4 + 1];

    // output: channel d = hin*128 + c gets evens (win=0); d+64 gets odds (win=1)
    long long o4 = (((long long)(b * 256 + hin * 128 + c)) * 128 + ho) * 32 + wo4;

    v4f s0 = {v0.x, v0.z, v1.x, v1.z};
    v4f s1 = {v0.y, v0.w, v1.y, v1.w};

    out[o4]           = s0;
    out[o4 + S1_OFF4] = s1;

    // x1 passthrough (16 floats) appended after y
    if (blockIdx.x == 0 && threadIdx.x < 16) {
        ((float*)out)[Y_ELEMS + threadIdx.x] = x1[threadIdx.x];
    }
}

extern "C" void kernel_launch(void* const* d_in, const int* in_sizes, int n_in,
                              void* d_out, int out_size, void* d_ws, size_t ws_size,
                              hipStream_t stream) {
    const v4f*   x0 = (const v4f*)d_in[0];
    const float* x1 = (const float*)d_in[1];
    v4f* out = (v4f*)d_out;

    const int block = 256;
    const int grid  = 32768;   // 8,388,608 threads, exact cover
    s2d_kernel<<<grid, block, 0, stream>>>(x0, x1, out);
}